// Round 10
// baseline (135.148 us; speedup 1.0000x reference)
//
#include <hip/hip_runtime.h>
#include <hip/hip_bf16.h>

#define B_ 128
#define L_ 128
#define J_ 64
#define E_ 128
#define H_ 2
#define HD 64
#define S_ 129          // L+1
#define M_ (B_ * S_)    // 16512 tokens
#define CAT_ 1000
#define LN_EPS 1e-5f

typedef __attribute__((ext_vector_type(8))) short bf16x8;
typedef __attribute__((ext_vector_type(4))) float f32x4;
typedef __hip_bfloat16 bf16;

__device__ inline float bf2f(unsigned short u) {
    union { unsigned int i; float f; } v; v.i = (unsigned int)u << 16; return v.f;
}
__device__ inline unsigned short f2bu(float f) {
    __hip_bfloat16 h = __float2bfloat16(f);
    return *reinterpret_cast<unsigned short*>(&h);
}

// ---------------------------------------------------------------------------
// prep: transpose+convert weights to bf16 Bt[N][K]; pad lin1/lin2; pad bias;
// z=8/9: convert cat/amount tables to bf16; z=10: zero hb accumulator.
// Wd bf16 offsets: q=0 k=16384 v=32768 o=49152 w1=65536 w2=81920
//                  lin1=98304 ([1024][128]) lin2=229376 ([1024][1024])
// ---------------------------------------------------------------------------
__global__ __launch_bounds__(256)
void prep_kernel(const float* __restrict__ Wq, const float* __restrict__ Wk,
                 const float* __restrict__ Wv, const float* __restrict__ Wo,
                 const float* __restrict__ W1, const float* __restrict__ W2,
                 const float* __restrict__ lin1W, const float* __restrict__ lin2W,
                 const float* __restrict__ lin1b,
                 const float* __restrict__ cat_table, const float* __restrict__ amount_table,
                 bf16* __restrict__ Wd, float* __restrict__ bias1024,
                 bf16* __restrict__ catb, bf16* __restrict__ amtb,
                 float* __restrict__ hb) {
    const int z = blockIdx.z;
    const int tid = threadIdx.x;
    if (z == 8) {   // cat_table -> bf16, 128000 elems
        const int gid = (blockIdx.x * 16 + blockIdx.y) * 256 + tid;
        for (int i = gid; i < 1000 * 128; i += 65536)
            catb[i] = __float2bfloat16(cat_table[i]);
        return;
    }
    if (z == 9) {   // amount_table -> bf16, 12800 elems
        const int gid = (blockIdx.x * 16 + blockIdx.y) * 256 + tid;
        for (int i = gid; i < 100 * 128; i += 65536)
            amtb[i] = __float2bfloat16(amount_table[i]);
        return;
    }
    if (z == 10) {  // zero hb [128][128] f32
        const int gid = (blockIdx.x * 16 + blockIdx.y) * 256 + tid;
        if (gid < B_ * E_) hb[gid] = 0.f;
        return;
    }
    const float* src; bf16* dst; int Kd, Nd, sK, sN;
    switch (z) {
        case 0: src = Wq;    dst = Wd;          Kd = 128;  Nd = 128;  sK = 128;  sN = 128;  break;
        case 1: src = Wk;    dst = Wd + 16384;  Kd = 128;  Nd = 128;  sK = 128;  sN = 128;  break;
        case 2: src = Wv;    dst = Wd + 32768;  Kd = 128;  Nd = 128;  sK = 128;  sN = 128;  break;
        case 3: src = Wo;    dst = Wd + 49152;  Kd = 128;  Nd = 128;  sK = 128;  sN = 128;  break;
        case 4: src = W1;    dst = Wd + 65536;  Kd = 128;  Nd = 128;  sK = 128;  sN = 128;  break;
        case 5: src = W2;    dst = Wd + 81920;  Kd = 128;  Nd = 128;  sK = 128;  sN = 128;  break;
        case 6: src = lin1W; dst = Wd + 98304;  Kd = 128;  Nd = 1024; sK = 128;  sN = 1000; break;
        default:src = lin2W; dst = Wd + 229376; Kd = 1024; Nd = 1024; sK = 1000; sN = 1000; break;
    }
    if (z == 7 && blockIdx.x == 0 && blockIdx.y == 0) {
        for (int i = tid; i < 1024; i += 256)
            bias1024[i] = (i < 1000) ? lin1b[i] : 0.f;
    }
    const int k0 = blockIdx.x * 64, n0 = blockIdx.y * 64;
    if (k0 >= Kd || n0 >= Nd) return;
    __shared__ float t[64][65];
    const int c = tid & 63, r0 = tid >> 6;
    #pragma unroll 4
    for (int i = 0; i < 16; ++i) {
        const int r = r0 + i * 4;
        const int gk = k0 + r, gn = n0 + c;
        t[r][c] = (gk < sK && gn < sN) ? src[(size_t)gk * sN + gn] : 0.f;
    }
    __syncthreads();
    #pragma unroll 4
    for (int i = 0; i < 16; ++i) {
        const int r = r0 + i * 4;
        dst[(size_t)(n0 + r) * Kd + (k0 + c)] = __float2bfloat16(t[c][r]);
    }
}

// ---------------------------------------------------------------------------
// Embedding v3: 2 tokens/block; per token 4 j-groups x 32 lanes x 4 elems.
// ---------------------------------------------------------------------------
__global__ __launch_bounds__(256)
void embed_kernel(const int* __restrict__ cat_arr, const int* __restrict__ dt_arr,
                  const int* __restrict__ amount_arr, const int* __restrict__ id_arr,
                  const float* __restrict__ id_table, const bf16* __restrict__ catb,
                  const bf16* __restrict__ amtb, const float* __restrict__ dt_table,
                  float* __restrict__ x) {
    __shared__ int cs[2][64];
    __shared__ int as_[2][64];
    __shared__ f32x4 red[2][4][32];
    const int tid = threadIdx.x;
    const int g2 = tid >> 7;              // token slot in block
    const int t7 = tid & 127;
    const int jg = t7 >> 5;               // j-group 0..3
    const int lg = t7 & 31;               // elems lg*4 .. lg*4+3
    const int t = blockIdx.x * 2 + g2;
    const int b = t / S_, s = t - b * S_;

    if (s > 0) {
        const int base = (b * L_ + (s - 1)) * J_;
        if (t7 < 64) cs[g2][t7] = cat_arr[base + t7];
        else         as_[g2][t7 - 64] = amount_arr[base + t7 - 64];
    }
    __syncthreads();

    f32x4 acc = {0.f, 0.f, 0.f, 0.f};
    if (s > 0) {
        #pragma unroll
        for (int jj = 0; jj < 16; ++jj) {
            const int j = jg * 16 + jj;
            const int c = cs[g2][j];
            const float m = (c != CAT_) ? 1.f : 0.f;
            const int ci = (c != CAT_) ? c : 0;
            const ushort4 cu = *(const ushort4*)(catb + (size_t)ci * E_ + lg * 4);
            const ushort4 au = *(const ushort4*)(amtb + (size_t)as_[g2][j] * E_ + lg * 4);
            acc[0] = fmaf(m, bf2f(cu.x) + bf2f(au.x), acc[0]);
            acc[1] = fmaf(m, bf2f(cu.y) + bf2f(au.y), acc[1]);
            acc[2] = fmaf(m, bf2f(cu.z) + bf2f(au.z), acc[2]);
            acc[3] = fmaf(m, bf2f(cu.w) + bf2f(au.w), acc[3]);
        }
    }
    red[g2][jg][lg] = acc;
    __syncthreads();

    if (jg == 0) {
        const size_t off = (size_t)t * E_ + lg * 4;
        if (s == 0) {
            *(float4*)(x + off) =
                *(const float4*)(id_table + (size_t)id_arr[b] * E_ + lg * 4);
        } else {
            const f32x4 a0 = red[g2][0][lg], a1 = red[g2][1][lg];
            const f32x4 a2 = red[g2][2][lg], a3 = red[g2][3][lg];
            const float4 dv = *(const float4*)(
                dt_table + (size_t)dt_arr[b * L_ + s - 1] * E_ + lg * 4);
            float4 o;
            o.x = a0[0] + a1[0] + a2[0] + a3[0] + dv.x;
            o.y = a0[1] + a1[1] + a2[1] + a3[1] + dv.y;
            o.z = a0[2] + a1[2] + a2[2] + a3[2] + dv.z;
            o.w = a0[3] + a1[3] + a2[3] + a3[3] + dv.w;
            *(float4*)(x + off) = o;
        }
    }
}

// ---------------------------------------------------------------------------
// bf16 MFMA GEMM (QKV / lin1 / lin2 paths)
// ---------------------------------------------------------------------------
template<bool RELU, bool LN, bool HASRES, bool OF32, bool OBF16, bool SPLITK,
         bool AF32, bool QKV>
__global__ __launch_bounds__(256)
void gemm_mfma(const void* __restrict__ Av, const bf16* __restrict__ Bt,
               const float* __restrict__ bias, const float* __restrict__ bias2,
               const float* __restrict__ bias3, const float* __restrict__ resid,
               float* __restrict__ Cf, bf16* __restrict__ Cb,
               bf16* __restrict__ Cb2, bf16* __restrict__ Cb3,
               const float* __restrict__ lng, const float* __restrict__ lnb,
               int K, int Nstride, int Nstore) {
    __shared__ bf16x8 Al[64 * 16];    // 16 KiB
    __shared__ bf16x8 Bl[128 * 16];   // 32 KiB
    const int tid = threadIdx.x;
    const int m0 = blockIdx.x * 64;
    const int n0 = QKV ? 0 : blockIdx.y * 128;
    const int w = tid >> 6, l = tid & 63;
    const int l15 = l & 15, g = l >> 4;
    f32x4 acc[8] = {};

    const bf16* BtX = Bt;
    const float* biasX = bias;
    bf16* CbX = Cb;
    if (QKV) {
        const int sel = blockIdx.y;
        BtX = Bt + sel * 16384;
        biasX = (sel == 0) ? bias : ((sel == 1) ? bias2 : bias3);
        CbX = (sel == 0) ? Cb : ((sel == 1) ? Cb2 : Cb3);
    }

    const int z = SPLITK ? blockIdx.z : 0;
    const int ksz = SPLITK ? (K / (int)gridDim.z) : K;
    const int kbeg = z * ksz;

    for (int kc = kbeg; kc < kbeg + ksz; kc += 128) {
        #pragma unroll
        for (int i = 0; i < 4; ++i) {
            const int lin = i * 256 + tid;
            const int r = lin >> 4, u = lin & 15;
            bf16x8 av;
            if (AF32) {
                const float* Af = (const float*)Av;
                const float4 f0 = *(const float4*)(Af + (size_t)(m0 + r) * K + kc + u * 8);
                const float4 f1 = *(const float4*)(Af + (size_t)(m0 + r) * K + kc + u * 8 + 4);
                av[0] = (short)f2bu(f0.x); av[1] = (short)f2bu(f0.y);
                av[2] = (short)f2bu(f0.z); av[3] = (short)f2bu(f0.w);
                av[4] = (short)f2bu(f1.x); av[5] = (short)f2bu(f1.y);
                av[6] = (short)f2bu(f1.z); av[7] = (short)f2bu(f1.w);
            } else {
                const bf16* Ab = (const bf16*)Av;
                av = *(const bf16x8*)(Ab + (size_t)(m0 + r) * K + kc + u * 8);
            }
            Al[r * 16 + (u ^ (r & 7))] = av;
        }
        #pragma unroll
        for (int i = 0; i < 8; ++i) {
            const int lin = i * 256 + tid;
            const int r = lin >> 4, u = lin & 15;
            Bl[r * 16 + (u ^ (r & 7))] =
                *(const bf16x8*)(BtX + (size_t)(n0 + r) * K + kc + u * 8);
        }
        __syncthreads();
        const int mr = w * 16 + l15;
        #pragma unroll
        for (int s = 0; s < 4; ++s) {
            const int ua = s * 4 + g;
            const bf16x8 a = Al[mr * 16 + (ua ^ (mr & 7))];
            #pragma unroll
            for (int nf = 0; nf < 8; ++nf) {
                const int nr = nf * 16 + l15;
                const bf16x8 b = Bl[nr * 16 + (ua ^ (nr & 7))];
                acc[nf] = __builtin_amdgcn_mfma_f32_16x16x32_bf16(a, b, acc[nf], 0, 0, 0);
            }
        }
        __syncthreads();
    }

    #pragma unroll
    for (int fr = 0; fr < 4; ++fr) {
        const int grow = m0 + w * 16 + g * 4 + fr;
        float v[8];
        float s1 = 0.f, s2 = 0.f;
        #pragma unroll
        for (int nf = 0; nf < 8; ++nf) {
            const int col = n0 + nf * 16 + l15;
            float xv = acc[nf][fr];
            if (!SPLITK && col < Nstore) xv += biasX[col];
            if (HASRES) xv += resid[(size_t)grow * Nstride + col];
            if (RELU) xv = fmaxf(xv, 0.f);
            v[nf] = xv;
            if (LN) { s1 += xv; s2 += xv * xv; }
        }
        if (LN) {
            #pragma unroll
            for (int off = 1; off < 16; off <<= 1) {
                s1 += __shfl_xor(s1, off);
                s2 += __shfl_xor(s2, off);
            }
            const float mu = s1 * (1.f / 128.f);
            const float rstd = rsqrtf(s2 * (1.f / 128.f) - mu * mu + LN_EPS);
            #pragma unroll
            for (int nf = 0; nf < 8; ++nf) {
                const int col = n0 + nf * 16 + l15;
                v[nf] = (v[nf] - mu) * rstd * lng[col] + lnb[col];
            }
        }
        float* Cfp = SPLITK ? (Cf + (size_t)z * (gridDim.x * 64) * Nstride) : Cf;
        #pragma unroll
        for (int nf = 0; nf < 8; ++nf) {
            const int col = n0 + nf * 16 + l15;
            if (col < Nstore) {
                if (OF32)  Cfp[(size_t)grow * Nstride + col] = v[nf];
                if (OBF16) CbX[(size_t)grow * Nstride + col] = __float2bfloat16(v[nf]);
            }
        }
    }
}

// ---------------------------------------------------------------------------
// Fused encoder tail + mean-pool. Per 64-row block:
//   X1 = LN1(X + O@Wo + bo); F1 = relu(X1@W1+b1); X = LN2(X1 + F1@W2 + b2);
//   hb[b,:] += X2 rows (s>0) / 128  (LDS partial sums -> 256 global atomics)
// ---------------------------------------------------------------------------
__global__ __launch_bounds__(256)
void encoder_tail(const bf16* __restrict__ Ob, const bf16* __restrict__ Wd,
                  const float* __restrict__ bo, const float* __restrict__ b1,
                  const float* __restrict__ b2,
                  const float* __restrict__ ln1g, const float* __restrict__ ln1b,
                  const float* __restrict__ ln2g, const float* __restrict__ ln2b,
                  float* __restrict__ X, float* __restrict__ hb) {
    __shared__ bf16x8 Al[64 * 16];    // 16 KiB
    __shared__ bf16x8 Bl[128 * 16];   // 32 KiB
    __shared__ float hbs[256];        // [2][128] per-block pool partials
    const int tid = threadIdx.x;
    const int m0 = blockIdx.x * 64;
    const int b0 = m0 / S_;
    const int w = tid >> 6, l = tid & 63;
    const int l15 = l & 15, g = l >> 4;
    bf16* Alb = (bf16*)Al;

    hbs[tid] = 0.f;

    // stage A = O tile, B = Wo
    #pragma unroll
    for (int i = 0; i < 4; ++i) {
        const int lin = i * 256 + tid;
        const int r = lin >> 4, u = lin & 15;
        Al[r * 16 + (u ^ (r & 7))] =
            *(const bf16x8*)(Ob + (size_t)(m0 + r) * E_ + u * 8);
    }
    #pragma unroll
    for (int i = 0; i < 8; ++i) {
        const int lin = i * 256 + tid;
        const int r = lin >> 4, u = lin & 15;
        Bl[r * 16 + (u ^ (r & 7))] =
            *(const bf16x8*)(Wd + 49152 + (size_t)r * E_ + u * 8);
    }
    __syncthreads();

    const int mr = w * 16 + l15;
    f32x4 acc[8];

    // ---- step 1: O@Wo ----
    #pragma unroll
    for (int nf = 0; nf < 8; ++nf) acc[nf] = f32x4{0.f, 0.f, 0.f, 0.f};
    #pragma unroll
    for (int s = 0; s < 4; ++s) {
        const int ua = s * 4 + g;
        const bf16x8 a = Al[mr * 16 + (ua ^ (mr & 7))];
        #pragma unroll
        for (int nf = 0; nf < 8; ++nf) {
            const int nr = nf * 16 + l15;
            acc[nf] = __builtin_amdgcn_mfma_f32_16x16x32_bf16(
                a, Bl[nr * 16 + (ua ^ (nr & 7))], acc[nf], 0, 0, 0);
        }
    }
    // ep1: x1 = LN1(acc + bo + X); keep f32 in regs; write bf16 to Al
    float x1[8][4];
    #pragma unroll
    for (int fr = 0; fr < 4; ++fr) {
        const int rloc = w * 16 + g * 4 + fr;
        const int grow = m0 + rloc;
        float s1 = 0.f, s2 = 0.f;
        float v[8];
        #pragma unroll
        for (int nf = 0; nf < 8; ++nf) {
            const int col = nf * 16 + l15;
            const float xv = acc[nf][fr] + bo[col] + X[(size_t)grow * E_ + col];
            v[nf] = xv; s1 += xv; s2 += xv * xv;
        }
        #pragma unroll
        for (int off = 1; off < 16; off <<= 1) {
            s1 += __shfl_xor(s1, off);
            s2 += __shfl_xor(s2, off);
        }
        const float mu = s1 * (1.f / 128.f);
        const float rstd = rsqrtf(s2 * (1.f / 128.f) - mu * mu + LN_EPS);
        #pragma unroll
        for (int nf = 0; nf < 8; ++nf) {
            const int col = nf * 16 + l15;
            const float xo = (v[nf] - mu) * rstd * ln1g[col] + ln1b[col];
            x1[nf][fr] = xo;
            const int u = col >> 3;
            Alb[(rloc * 16 + (u ^ (rloc & 7))) * 8 + (col & 7)] = __float2bfloat16(xo);
        }
    }

    // ---- step 2: relu(x1@W1 + b1) ----
    __syncthreads();                       // all waves done reading Bl(Wo)
    #pragma unroll
    for (int i = 0; i < 8; ++i) {
        const int lin = i * 256 + tid;
        const int r = lin >> 4, u = lin & 15;
        Bl[r * 16 + (u ^ (r & 7))] =
            *(const bf16x8*)(Wd + 65536 + (size_t)r * E_ + u * 8);
    }
    __syncthreads();
    #pragma unroll
    for (int nf = 0; nf < 8; ++nf) acc[nf] = f32x4{0.f, 0.f, 0.f, 0.f};
    #pragma unroll
    for (int s = 0; s < 4; ++s) {
        const int ua = s * 4 + g;
        const bf16x8 a = Al[mr * 16 + (ua ^ (mr & 7))];
        #pragma unroll
        for (int nf = 0; nf < 8; ++nf) {
            const int nr = nf * 16 + l15;
            acc[nf] = __builtin_amdgcn_mfma_f32_16x16x32_bf16(
                a, Bl[nr * 16 + (ua ^ (nr & 7))], acc[nf], 0, 0, 0);
        }
    }
    #pragma unroll
    for (int fr = 0; fr < 4; ++fr) {
        const int rloc = w * 16 + g * 4 + fr;
        #pragma unroll
        for (int nf = 0; nf < 8; ++nf) {
            const int col = nf * 16 + l15;
            const float f = fmaxf(acc[nf][fr] + b1[col], 0.f);
            const int u = col >> 3;
            Alb[(rloc * 16 + (u ^ (rloc & 7))) * 8 + (col & 7)] = __float2bfloat16(f);
        }
    }

    // ---- step 3: LN2(x1 + f1@W2 + b2) -> X ; pool partials -> hbs ----
    __syncthreads();
    #pragma unroll
    for (int i = 0; i < 8; ++i) {
        const int lin = i * 256 + tid;
        const int r = lin >> 4, u = lin & 15;
        Bl[r * 16 + (u ^ (r & 7))] =
            *(const bf16x8*)(Wd + 81920 + (size_t)r * E_ + u * 8);
    }
    __syncthreads();
    #pragma unroll
    for (int nf = 0; nf < 8; ++nf) acc[nf] = f32x4{0.f, 0.f, 0.f, 0.f};
    #pragma unroll
    for (int s = 0; s < 4; ++s) {
        const int ua = s * 4 + g;
        const bf16x8 a = Al[mr * 16 + (ua ^ (mr & 7))];
        #pragma unroll
        for (int nf = 0; nf < 8; ++nf) {
            const int nr = nf * 16 + l15;
            acc[nf] = __builtin_amdgcn_mfma_f32_16x16x32_bf16(
                a, Bl[nr * 16 + (ua ^ (nr & 7))], acc[nf], 0, 0, 0);
        }
    }
    #pragma unroll
    for (int fr = 0; fr < 4; ++fr) {
        const int grow = m0 + w * 16 + g * 4 + fr;
        const int bb = grow / S_, ss = grow - bb * S_;
        const int bl = bb - b0;
        float s1 = 0.f, s2 = 0.f;
        float v[8];
        #pragma unroll
        for (int nf = 0; nf < 8; ++nf) {
            const int col = nf * 16 + l15;
            const float xv = acc[nf][fr] + b2[col] + x1[nf][fr];
            v[nf] = xv; s1 += xv; s2 += xv * xv;
        }
        #pragma unroll
        for (int off = 1; off < 16; off <<= 1) {
            s1 += __shfl_xor(s1, off);
            s2 += __shfl_xor(s2, off);
        }
        const float mu = s1 * (1.f / 128.f);
        const float rstd = rsqrtf(s2 * (1.f / 128.f) - mu * mu + LN_EPS);
        #pragma unroll
        for (int nf = 0; nf < 8; ++nf) {
            const int col = nf * 16 + l15;
            const float xo = (v[nf] - mu) * rstd * ln2g[col] + ln2b[col];
            X[(size_t)grow * E_ + col] = xo;
            if (ss > 0) atomicAdd(&hbs[bl * 128 + col], xo * (1.f / 128.f));
        }
    }

    __syncthreads();
    {
        const int bl = tid >> 7, col = tid & 127;
        const int bb = b0 + bl;
        if (bb < B_) atomicAdd(&hb[bb * 128 + col], hbs[tid]);
    }
}

// ---------------------------------------------------------------------------
// MFMA attention v2 (round 8) + vectorized V staging.
// ---------------------------------------------------------------------------
__global__ __launch_bounds__(256)
void attn_mfma(bf16* __restrict__ qb, const bf16* __restrict__ kb,
               const bf16* __restrict__ vb) {
    __shared__ __align__(16) bf16x8 Ks[144 * 8];      // 18 KiB, swizzled
    __shared__ __align__(16) short Vt[64 * 168];      // 21 KiB, V^T
    __shared__ __align__(16) bf16  Pb[4][16 * 168];   // 21 KiB, per-wave P
    const int tid = threadIdx.x;
    const int w = tid >> 6, l = tid & 63;
    const int l15 = l & 15, g = l >> 4;
    const int blk = blockIdx.x;
    const int half = blk & 1;
    const int h = (blk >> 1) & (H_ - 1);
    const int b = blk >> 2;
    const size_t base = ((size_t)b * S_) * E_ + h * HD;

    for (int idx = tid; idx < 144 * 8; idx += 256) {
        const int r = idx >> 3, u = idx & 7;
        bf16x8 kv = {0, 0, 0, 0, 0, 0, 0, 0};
        if (r < S_) kv = *(const bf16x8*)(kb + base + (size_t)r * E_ + u * 8);
        Ks[r * 8 + (u ^ (r & 7))] = kv;
    }
    // V transposed: vectorized global reads (bf16x8 per row-span of 8 d)
    for (int idx = tid; idx < S_ * 8; idx += 256) {       // 1032
        const int t = idx >> 3, d8 = (idx & 7) << 3;
        const bf16x8 vv = *(const bf16x8*)(vb + base + (size_t)t * E_ + d8);
        #pragma unroll
        for (int j = 0; j < 8; ++j)
            Vt[(d8 + j) * 168 + t] = vv[j];
    }
    for (int idx = tid; idx < 64 * 39; idx += 256) {      // zero pads t=129..167
        const int d = idx / 39, t = 129 + (idx - (idx / 39) * 39);
        Vt[d * 168 + t] = 0;
    }
    __syncthreads();

    bf16* P = Pb[w];
    for (int rt = (half ? 5 : 0) + w; rt < (half ? 9 : 5); rt += 4) {
        const int qr0 = rt * 16 + l15;
        const int qrow = (qr0 < S_) ? qr0 : (S_ - 1);
        const bf16x8 aq0 = *(const bf16x8*)(qb + base + (size_t)qrow * E_ + g * 8);
        const bf16x8 aq1 = *(const bf16x8*)(qb + base + (size_t)qrow * E_ + 32 + g * 8);

        f32x4 acc[9];
        #pragma unroll
        for (int ct = 0; ct < 9; ++ct) {
            const int kr = ct * 16 + l15;
            f32x4 a = {0.f, 0.f, 0.f, 0.f};
            a = __builtin_amdgcn_mfma_f32_16x16x32_bf16(
                    aq0, Ks[kr * 8 + (g ^ (kr & 7))], a, 0, 0, 0);
            a = __builtin_amdgcn_mfma_f32_16x16x32_bf16(
                    aq1, Ks[kr * 8 + ((4 + g) ^ (kr & 7))], a, 0, 0, 0);
            acc[ct] = a;
        }

        const bool tail = (l15 != 0);
        float mx[4] = {-1e30f, -1e30f, -1e30f, -1e30f};
        #pragma unroll
        for (int ct = 0; ct < 9; ++ct)
            #pragma unroll
            for (int r = 0; r < 4; ++r) {
                const float v = acc[ct][r] * 0.125f;
                acc[ct][r] = v;
                if (ct < 8 || !tail) mx[r] = fmaxf(mx[r], v);
            }
        #pragma unroll
        for (int r = 0; r < 4; ++r)
            #pragma unroll
            for (int off = 1; off < 16; off <<= 1)
                mx[r] = fmaxf(mx[r], __shfl_xor(mx[r], off));
        float sm[4] = {0.f, 0.f, 0.f, 0.f};
        #pragma unroll
        for (int ct = 0; ct < 9; ++ct)
            #pragma unroll
            for (int r = 0; r < 4; ++r) {
                const float p = (ct < 8 || !tail) ? __expf(acc[ct][r] - mx[r]) : 0.f;
                acc[ct][r] = p;
                sm[r] += p;
            }
        #pragma unroll
        for (int r = 0; r < 4; ++r) {
            #pragma unroll
            for (int off = 1; off < 16; off <<= 1)
                sm[r] += __shfl_xor(sm[r], off);
            sm[r] = 1.f / sm[r];
        }

        #pragma unroll
        for (int ct = 0; ct < 9; ++ct)
            #pragma unroll
            for (int r = 0; r < 4; ++r)
                P[(g * 4 + r) * 168 + ct * 16 + l15] =
                    __float2bfloat16(acc[ct][r] * sm[r]);
        #pragma unroll
        for (int r = 0; r < 4; ++r)
            P[(g * 4 + r) * 168 + 144 + l15] = __float2bfloat16(0.f);

        #pragma unroll
        for (int co = 0; co < 4; ++co) {
            f32x4 o = {0.f, 0.f, 0.f, 0.f};
            #pragma unroll
            for (int kc = 0; kc < 5; ++kc) {
                const bf16x8 pa = *(const bf16x8*)(P + l15 * 168 + kc * 32 + g * 8);
                const bf16x8 vv = *(const bf16x8*)(Vt + (co * 16 + l15) * 168 + kc * 32 + g * 8);
                o = __builtin_amdgcn_mfma_f32_16x16x32_bf16(pa, vv, o, 0, 0, 0);
            }
            #pragma unroll
            for (int r = 0; r < 4; ++r) {
                const int orow = rt * 16 + g * 4 + r;
                if (orow < S_)
                    qb[base + (size_t)orow * E_ + co * 16 + l15] =
                        __float2bfloat16(o[r]);
            }
        }
    }
}

// reduce split-K partials [8][128][1024] -> out[128][1000] (+bias)
__global__ __launch_bounds__(256)
void splitk_reduce(const float* __restrict__ part, const float* __restrict__ bias,
                   float* __restrict__ out) {
    const int i = blockIdx.x * 256 + threadIdx.x;
    if (i >= B_ * CAT_) return;
    const int m = i / CAT_, n = i - m * CAT_;
    float v = bias[n];
    #pragma unroll
    for (int z = 0; z < 8; ++z) v += part[(size_t)z * 131072 + m * 1024 + n];
    out[i] = v;
}

// ---------------------------------------------------------------------------
extern "C" void kernel_launch(void* const* d_in, const int* in_sizes, int n_in,
                              void* d_out, int out_size, void* d_ws, size_t ws_size,
                              hipStream_t stream) {
    const int* cat_arr      = (const int*)d_in[0];
    const int* dt_arr       = (const int*)d_in[1];
    const int* amount_arr   = (const int*)d_in[2];
    const int* id_arr       = (const int*)d_in[3];
    const float* id_table   = (const float*)d_in[4];
    const float* cat_table  = (const float*)d_in[5];
    const float* amount_tab = (const float*)d_in[6];
    const float* dt_table   = (const float*)d_in[7];
    const float* Wq = (const float*)d_in[8];  const float* bq = (const float*)d_in[9];
    const float* Wk = (const float*)d_in[10]; const float* bk = (const float*)d_in[11];
    const float* Wv = (const float*)d_in[12]; const float* bv = (const float*)d_in[13];
    const float* Wo = (const float*)d_in[14]; const float* bo = (const float*)d_in[15];
    const float* ln1_g = (const float*)d_in[16]; const float* ln1_b = (const float*)d_in[17];
    const float* W1 = (const float*)d_in[18]; const float* b1 = (const float*)d_in[19];
    const float* W2 = (const float*)d_in[20]; const float* b2 = (const float*)d_in[21];
    const float* ln2_g = (const float*)d_in[22]; const float* ln2_b = (const float*)d_in[23];
    const float* lin1_W = (const float*)d_in[24]; const float* lin1_b = (const float*)d_in[25];
    const float* lin2_W = (const float*)d_in[26]; const float* lin2_b = (const float*)d_in[27];
    float* out = (float*)d_out;
    float* ws = (float*)d_ws;

    // Workspace (floats), total ~24.0 MiB:
    //   X[ME] | C0 bf16[ME] | D0 bf16[ME] | E0 bf16[ME] | Wd | bias1024 | catb | amtb | hb
    const size_t ME = (size_t)M_ * E_;           // 2,113,536
    float* X  = ws;                               // f32 x -> x2 (in-place)
    bf16* C0  = (bf16*)(ws + ME);                 // Kb
    bf16* D0  = (bf16*)(ws + ME + ME / 2);        // Qb -> Ob -> a1b
    bf16* E0  = (bf16*)(ws + 2 * ME);             // Vb -> (f32 prt)
    bf16* Wd  = (bf16*)(ws + 2 * ME + ME / 2);    // 1,277,952 bf16
    float* bias1024 = ws + 2 * ME + ME / 2 + 638976;
    bf16* catb = (bf16*)(bias1024 + 1024);        // [1000][128] bf16
    bf16* amtb = catb + 128000;                   // [100][128] bf16
    float* hb  = (float*)(amtb + 12800);          // [128][128] f32
    bf16* a1b = D0 + 16384;                       // [128][1024]
    float* prt = (float*)E0;                      // [8][128][1024] f32 (4 MiB)

    prep_kernel<<<dim3(16, 16, 11), 256, 0, stream>>>(
        Wq, Wk, Wv, Wo, W1, W2, lin1_W, lin2_W, lin1_b,
        cat_table, amount_tab, Wd, bias1024, catb, amtb, hb);

    embed_kernel<<<M_ / 2, 256, 0, stream>>>(cat_arr, dt_arr, amount_arr, id_arr,
                                             id_table, catb, amtb, dt_table, X);

    // Fused QKV from f32 X: sel 0->Q(D0), 1->K(C0), 2->V(E0)
    gemm_mfma<false,false,false,false,true,false,true,true>
        <<<dim3(M_ / 64, 3), 256, 0, stream>>>(
        X, Wd, bq, bk, bv, nullptr, nullptr, D0, C0, E0, nullptr, nullptr,
        128, 128, 128);

    attn_mfma<<<B_ * H_ * 2, 256, 0, stream>>>(D0, C0, E0);   // Ob -> D0

    // Fused tail + pool: X = LN2(...), hb += pooled means
    encoder_tail<<<M_ / 64, 256, 0, stream>>>(
        D0, Wd, bo, b1, b2, ln1_g, ln1_b, ln2_g, ln2_b, X, hb);

    // a1b = relu(hb@lin1 + b) [128][1024] (A is f32 via AF32 staging)
    gemm_mfma<true,false,false,false,true,false,true,false>
        <<<dim3(2, 8), 256, 0, stream>>>(
        hb, Wd + 98304, bias1024, nullptr, nullptr, nullptr, nullptr, a1b,
        nullptr, nullptr, nullptr, nullptr, 128, 1024, 1024);
    // prt[z] = a1b@lin2 partials (K=1024 split 8 ways)
    gemm_mfma<false,false,false,true,false,true,false,false>
        <<<dim3(2, 8, 8), 256, 0, stream>>>(
        a1b, Wd + 229376, nullptr, nullptr, nullptr, nullptr, prt, nullptr,
        nullptr, nullptr, nullptr, nullptr, 1024, 1024, 1024);
    splitk_reduce<<<(B_ * CAT_ + 255) / 256, 256, 0, stream>>>(prt, lin2_b, out);
}

// Round 11
// 128.823 us; speedup vs baseline: 1.0491x; 1.0491x over previous
//
#include <hip/hip_runtime.h>
#include <hip/hip_bf16.h>

#define B_ 128
#define L_ 128
#define J_ 64
#define E_ 128
#define H_ 2
#define HD 64
#define S_ 129          // L+1
#define M_ (B_ * S_)    // 16512 tokens
#define CAT_ 1000
#define LN_EPS 1e-5f

typedef __attribute__((ext_vector_type(8))) short bf16x8;
typedef __attribute__((ext_vector_type(4))) float f32x4;
typedef __hip_bfloat16 bf16;

__device__ inline float bf2f(unsigned short u) {
    union { unsigned int i; float f; } v; v.i = (unsigned int)u << 16; return v.f;
}
__device__ inline unsigned short f2bu(float f) {
    __hip_bfloat16 h = __float2bfloat16(f);
    return *reinterpret_cast<unsigned short*>(&h);
}

// ---------------------------------------------------------------------------
// prep: transpose+convert weights to bf16 Bt[N][K]; pad lin1/lin2; pad bias;
// z=8/9: tables->bf16; z=10: zero hb; z=11: out = lin2 bias (every call).
// Wd bf16 offsets: q=0 k=16384 v=32768 o=49152 w1=65536 w2=81920
//                  lin1=98304 ([1024][128]) lin2=229376 ([1024][1024])
// ---------------------------------------------------------------------------
__global__ __launch_bounds__(256)
void prep_kernel(const float* __restrict__ Wq, const float* __restrict__ Wk,
                 const float* __restrict__ Wv, const float* __restrict__ Wo,
                 const float* __restrict__ W1, const float* __restrict__ W2,
                 const float* __restrict__ lin1W, const float* __restrict__ lin2W,
                 const float* __restrict__ lin1b, const float* __restrict__ lin2b,
                 const float* __restrict__ cat_table, const float* __restrict__ amount_table,
                 bf16* __restrict__ Wd, float* __restrict__ bias1024,
                 bf16* __restrict__ catb, bf16* __restrict__ amtb,
                 float* __restrict__ hb, float* __restrict__ outp) {
    const int z = blockIdx.z;
    const int tid = threadIdx.x;
    if (z == 8) {   // cat_table -> bf16, 128000 elems
        const int gid = (blockIdx.x * 16 + blockIdx.y) * 256 + tid;
        for (int i = gid; i < 1000 * 128; i += 65536)
            catb[i] = __float2bfloat16(cat_table[i]);
        return;
    }
    if (z == 9) {   // amount_table -> bf16, 12800 elems
        const int gid = (blockIdx.x * 16 + blockIdx.y) * 256 + tid;
        for (int i = gid; i < 100 * 128; i += 65536)
            amtb[i] = __float2bfloat16(amount_table[i]);
        return;
    }
    if (z == 10) {  // zero hb [128][128] f32 (tail atomics accumulate into it)
        const int gid = (blockIdx.x * 16 + blockIdx.y) * 256 + tid;
        if (gid < B_ * E_) hb[gid] = 0.f;
        return;
    }
    if (z == 11) {  // out[128][1000] = lin2 bias (lin2 atomically adds partials)
        const int gid = (blockIdx.x * 16 + blockIdx.y) * 256 + tid;
        for (int i = gid; i < B_ * CAT_; i += 65536)
            outp[i] = lin2b[i % CAT_];
        return;
    }
    const float* src; bf16* dst; int Kd, Nd, sK, sN;
    switch (z) {
        case 0: src = Wq;    dst = Wd;          Kd = 128;  Nd = 128;  sK = 128;  sN = 128;  break;
        case 1: src = Wk;    dst = Wd + 16384;  Kd = 128;  Nd = 128;  sK = 128;  sN = 128;  break;
        case 2: src = Wv;    dst = Wd + 32768;  Kd = 128;  Nd = 128;  sK = 128;  sN = 128;  break;
        case 3: src = Wo;    dst = Wd + 49152;  Kd = 128;  Nd = 128;  sK = 128;  sN = 128;  break;
        case 4: src = W1;    dst = Wd + 65536;  Kd = 128;  Nd = 128;  sK = 128;  sN = 128;  break;
        case 5: src = W2;    dst = Wd + 81920;  Kd = 128;  Nd = 128;  sK = 128;  sN = 128;  break;
        case 6: src = lin1W; dst = Wd + 98304;  Kd = 128;  Nd = 1024; sK = 128;  sN = 1000; break;
        default:src = lin2W; dst = Wd + 229376; Kd = 1024; Nd = 1024; sK = 1000; sN = 1000; break;
    }
    if (z == 7 && blockIdx.x == 0 && blockIdx.y == 0) {
        for (int i = tid; i < 1024; i += 256)
            bias1024[i] = (i < 1000) ? lin1b[i] : 0.f;
    }
    const int k0 = blockIdx.x * 64, n0 = blockIdx.y * 64;
    if (k0 >= Kd || n0 >= Nd) return;
    __shared__ float t[64][65];
    const int c = tid & 63, r0 = tid >> 6;
    #pragma unroll 4
    for (int i = 0; i < 16; ++i) {
        const int r = r0 + i * 4;
        const int gk = k0 + r, gn = n0 + c;
        t[r][c] = (gk < sK && gn < sN) ? src[(size_t)gk * sN + gn] : 0.f;
    }
    __syncthreads();
    #pragma unroll 4
    for (int i = 0; i < 16; ++i) {
        const int r = r0 + i * 4;
        dst[(size_t)(n0 + r) * Kd + (k0 + c)] = __float2bfloat16(t[c][r]);
    }
}

// ---------------------------------------------------------------------------
// Embedding v3: 2 tokens/block; per token 4 j-groups x 32 lanes x 4 elems.
// ---------------------------------------------------------------------------
__global__ __launch_bounds__(256)
void embed_kernel(const int* __restrict__ cat_arr, const int* __restrict__ dt_arr,
                  const int* __restrict__ amount_arr, const int* __restrict__ id_arr,
                  const float* __restrict__ id_table, const bf16* __restrict__ catb,
                  const bf16* __restrict__ amtb, const float* __restrict__ dt_table,
                  float* __restrict__ x) {
    __shared__ int cs[2][64];
    __shared__ int as_[2][64];
    __shared__ f32x4 red[2][4][32];
    const int tid = threadIdx.x;
    const int g2 = tid >> 7;              // token slot in block
    const int t7 = tid & 127;
    const int jg = t7 >> 5;               // j-group 0..3
    const int lg = t7 & 31;               // elems lg*4 .. lg*4+3
    const int t = blockIdx.x * 2 + g2;
    const int b = t / S_, s = t - b * S_;

    if (s > 0) {
        const int base = (b * L_ + (s - 1)) * J_;
        if (t7 < 64) cs[g2][t7] = cat_arr[base + t7];
        else         as_[g2][t7 - 64] = amount_arr[base + t7 - 64];
    }
    __syncthreads();

    f32x4 acc = {0.f, 0.f, 0.f, 0.f};
    if (s > 0) {
        #pragma unroll
        for (int jj = 0; jj < 16; ++jj) {
            const int j = jg * 16 + jj;
            const int c = cs[g2][j];
            const float m = (c != CAT_) ? 1.f : 0.f;
            const int ci = (c != CAT_) ? c : 0;
            const ushort4 cu = *(const ushort4*)(catb + (size_t)ci * E_ + lg * 4);
            const ushort4 au = *(const ushort4*)(amtb + (size_t)as_[g2][j] * E_ + lg * 4);
            acc[0] = fmaf(m, bf2f(cu.x) + bf2f(au.x), acc[0]);
            acc[1] = fmaf(m, bf2f(cu.y) + bf2f(au.y), acc[1]);
            acc[2] = fmaf(m, bf2f(cu.z) + bf2f(au.z), acc[2]);
            acc[3] = fmaf(m, bf2f(cu.w) + bf2f(au.w), acc[3]);
        }
    }
    red[g2][jg][lg] = acc;
    __syncthreads();

    if (jg == 0) {
        const size_t off = (size_t)t * E_ + lg * 4;
        if (s == 0) {
            *(float4*)(x + off) =
                *(const float4*)(id_table + (size_t)id_arr[b] * E_ + lg * 4);
        } else {
            const f32x4 a0 = red[g2][0][lg], a1 = red[g2][1][lg];
            const f32x4 a2 = red[g2][2][lg], a3 = red[g2][3][lg];
            const float4 dv = *(const float4*)(
                dt_table + (size_t)dt_arr[b * L_ + s - 1] * E_ + lg * 4);
            float4 o;
            o.x = a0[0] + a1[0] + a2[0] + a3[0] + dv.x;
            o.y = a0[1] + a1[1] + a2[1] + a3[1] + dv.y;
            o.z = a0[2] + a1[2] + a2[2] + a3[2] + dv.z;
            o.w = a0[3] + a1[3] + a2[3] + a3[3] + dv.w;
            *(float4*)(x + off) = o;
        }
    }
}

// ---------------------------------------------------------------------------
// bf16 MFMA GEMM (QKV / lin1 / lin2 paths). ATOM: atomicAdd partials into Cf.
// ---------------------------------------------------------------------------
template<bool RELU, bool LN, bool HASRES, bool OF32, bool OBF16, bool SPLITK,
         bool AF32, bool QKV, bool ATOM>
__global__ __launch_bounds__(256)
void gemm_mfma(const void* __restrict__ Av, const bf16* __restrict__ Bt,
               const float* __restrict__ bias, const float* __restrict__ bias2,
               const float* __restrict__ bias3, const float* __restrict__ resid,
               float* __restrict__ Cf, bf16* __restrict__ Cb,
               bf16* __restrict__ Cb2, bf16* __restrict__ Cb3,
               const float* __restrict__ lng, const float* __restrict__ lnb,
               int K, int Nstride, int Nstore) {
    __shared__ bf16x8 Al[64 * 16];    // 16 KiB
    __shared__ bf16x8 Bl[128 * 16];   // 32 KiB
    const int tid = threadIdx.x;
    const int m0 = blockIdx.x * 64;
    const int n0 = QKV ? 0 : blockIdx.y * 128;
    const int w = tid >> 6, l = tid & 63;
    const int l15 = l & 15, g = l >> 4;
    f32x4 acc[8] = {};

    const bf16* BtX = Bt;
    const float* biasX = bias;
    bf16* CbX = Cb;
    if (QKV) {
        const int sel = blockIdx.y;
        BtX = Bt + sel * 16384;
        biasX = (sel == 0) ? bias : ((sel == 1) ? bias2 : bias3);
        CbX = (sel == 0) ? Cb : ((sel == 1) ? Cb2 : Cb3);
    }

    const int z = SPLITK ? blockIdx.z : 0;
    const int ksz = SPLITK ? (K / (int)gridDim.z) : K;
    const int kbeg = z * ksz;

    for (int kc = kbeg; kc < kbeg + ksz; kc += 128) {
        #pragma unroll
        for (int i = 0; i < 4; ++i) {
            const int lin = i * 256 + tid;
            const int r = lin >> 4, u = lin & 15;
            bf16x8 av;
            if (AF32) {
                const float* Af = (const float*)Av;
                const float4 f0 = *(const float4*)(Af + (size_t)(m0 + r) * K + kc + u * 8);
                const float4 f1 = *(const float4*)(Af + (size_t)(m0 + r) * K + kc + u * 8 + 4);
                av[0] = (short)f2bu(f0.x); av[1] = (short)f2bu(f0.y);
                av[2] = (short)f2bu(f0.z); av[3] = (short)f2bu(f0.w);
                av[4] = (short)f2bu(f1.x); av[5] = (short)f2bu(f1.y);
                av[6] = (short)f2bu(f1.z); av[7] = (short)f2bu(f1.w);
            } else {
                const bf16* Ab = (const bf16*)Av;
                av = *(const bf16x8*)(Ab + (size_t)(m0 + r) * K + kc + u * 8);
            }
            Al[r * 16 + (u ^ (r & 7))] = av;
        }
        #pragma unroll
        for (int i = 0; i < 8; ++i) {
            const int lin = i * 256 + tid;
            const int r = lin >> 4, u = lin & 15;
            Bl[r * 16 + (u ^ (r & 7))] =
                *(const bf16x8*)(BtX + (size_t)(n0 + r) * K + kc + u * 8);
        }
        __syncthreads();
        const int mr = w * 16 + l15;
        #pragma unroll
        for (int s = 0; s < 4; ++s) {
            const int ua = s * 4 + g;
            const bf16x8 a = Al[mr * 16 + (ua ^ (mr & 7))];
            #pragma unroll
            for (int nf = 0; nf < 8; ++nf) {
                const int nr = nf * 16 + l15;
                const bf16x8 b = Bl[nr * 16 + (ua ^ (nr & 7))];
                acc[nf] = __builtin_amdgcn_mfma_f32_16x16x32_bf16(a, b, acc[nf], 0, 0, 0);
            }
        }
        __syncthreads();
    }

    #pragma unroll
    for (int fr = 0; fr < 4; ++fr) {
        const int grow = m0 + w * 16 + g * 4 + fr;
        float v[8];
        float s1 = 0.f, s2 = 0.f;
        #pragma unroll
        for (int nf = 0; nf < 8; ++nf) {
            const int col = n0 + nf * 16 + l15;
            float xv = acc[nf][fr];
            if (!SPLITK && col < Nstore) xv += biasX[col];
            if (HASRES) xv += resid[(size_t)grow * Nstride + col];
            if (RELU) xv = fmaxf(xv, 0.f);
            v[nf] = xv;
            if (LN) { s1 += xv; s2 += xv * xv; }
        }
        if (LN) {
            #pragma unroll
            for (int off = 1; off < 16; off <<= 1) {
                s1 += __shfl_xor(s1, off);
                s2 += __shfl_xor(s2, off);
            }
            const float mu = s1 * (1.f / 128.f);
            const float rstd = rsqrtf(s2 * (1.f / 128.f) - mu * mu + LN_EPS);
            #pragma unroll
            for (int nf = 0; nf < 8; ++nf) {
                const int col = n0 + nf * 16 + l15;
                v[nf] = (v[nf] - mu) * rstd * lng[col] + lnb[col];
            }
        }
        float* Cfp = (SPLITK && !ATOM) ? (Cf + (size_t)z * (gridDim.x * 64) * Nstride) : Cf;
        #pragma unroll
        for (int nf = 0; nf < 8; ++nf) {
            const int col = n0 + nf * 16 + l15;
            if (col < Nstore) {
                if (OF32) {
                    if (ATOM) atomicAdd(&Cfp[(size_t)grow * Nstride + col], v[nf]);
                    else      Cfp[(size_t)grow * Nstride + col] = v[nf];
                }
                if (OBF16) CbX[(size_t)grow * Nstride + col] = __float2bfloat16(v[nf]);
            }
        }
    }
}

// ---------------------------------------------------------------------------
// Fused encoder tail + mean-pool (contention-free reduction).
//   X1 = LN1(X + O@Wo + bo); F1 = relu(X1@W1+b1); X = LN2(X1 + F1@W2 + b2);
//   pool: per-thread register partials -> shfl over g -> 4KB LDS over waves
//   -> 256 uncontended global atomicAdds into hb.
// ---------------------------------------------------------------------------
__global__ __launch_bounds__(256)
void encoder_tail(const bf16* __restrict__ Ob, const bf16* __restrict__ Wd,
                  const float* __restrict__ bo, const float* __restrict__ b1,
                  const float* __restrict__ b2,
                  const float* __restrict__ ln1g, const float* __restrict__ ln1b,
                  const float* __restrict__ ln2g, const float* __restrict__ ln2b,
                  float* __restrict__ X, float* __restrict__ hb) {
    __shared__ bf16x8 Al[64 * 16];    // 16 KiB
    __shared__ bf16x8 Bl[128 * 16];   // 32 KiB
    __shared__ float hbw[4][2][128];  // 4 KiB pool partials
    const int tid = threadIdx.x;
    const int m0 = blockIdx.x * 64;
    const int b0 = m0 / S_;
    const int w = tid >> 6, l = tid & 63;
    const int l15 = l & 15, g = l >> 4;
    bf16* Alb = (bf16*)Al;

    // stage A = O tile, B = Wo
    #pragma unroll
    for (int i = 0; i < 4; ++i) {
        const int lin = i * 256 + tid;
        const int r = lin >> 4, u = lin & 15;
        Al[r * 16 + (u ^ (r & 7))] =
            *(const bf16x8*)(Ob + (size_t)(m0 + r) * E_ + u * 8);
    }
    #pragma unroll
    for (int i = 0; i < 8; ++i) {
        const int lin = i * 256 + tid;
        const int r = lin >> 4, u = lin & 15;
        Bl[r * 16 + (u ^ (r & 7))] =
            *(const bf16x8*)(Wd + 49152 + (size_t)r * E_ + u * 8);
    }
    __syncthreads();

    const int mr = w * 16 + l15;
    f32x4 acc[8];

    // ---- step 1: O@Wo ----
    #pragma unroll
    for (int nf = 0; nf < 8; ++nf) acc[nf] = f32x4{0.f, 0.f, 0.f, 0.f};
    #pragma unroll
    for (int s = 0; s < 4; ++s) {
        const int ua = s * 4 + g;
        const bf16x8 a = Al[mr * 16 + (ua ^ (mr & 7))];
        #pragma unroll
        for (int nf = 0; nf < 8; ++nf) {
            const int nr = nf * 16 + l15;
            acc[nf] = __builtin_amdgcn_mfma_f32_16x16x32_bf16(
                a, Bl[nr * 16 + (ua ^ (nr & 7))], acc[nf], 0, 0, 0);
        }
    }
    // ep1: x1 = LN1(acc + bo + X); keep f32 in regs; write bf16 to Al
    float x1[8][4];
    #pragma unroll
    for (int fr = 0; fr < 4; ++fr) {
        const int rloc = w * 16 + g * 4 + fr;
        const int grow = m0 + rloc;
        float s1 = 0.f, s2 = 0.f;
        float v[8];
        #pragma unroll
        for (int nf = 0; nf < 8; ++nf) {
            const int col = nf * 16 + l15;
            const float xv = acc[nf][fr] + bo[col] + X[(size_t)grow * E_ + col];
            v[nf] = xv; s1 += xv; s2 += xv * xv;
        }
        #pragma unroll
        for (int off = 1; off < 16; off <<= 1) {
            s1 += __shfl_xor(s1, off);
            s2 += __shfl_xor(s2, off);
        }
        const float mu = s1 * (1.f / 128.f);
        const float rstd = rsqrtf(s2 * (1.f / 128.f) - mu * mu + LN_EPS);
        #pragma unroll
        for (int nf = 0; nf < 8; ++nf) {
            const int col = nf * 16 + l15;
            const float xo = (v[nf] - mu) * rstd * ln1g[col] + ln1b[col];
            x1[nf][fr] = xo;
            const int u = col >> 3;
            Alb[(rloc * 16 + (u ^ (rloc & 7))) * 8 + (col & 7)] = __float2bfloat16(xo);
        }
    }

    // ---- step 2: relu(x1@W1 + b1) ----
    __syncthreads();                       // all waves done reading Bl(Wo)
    #pragma unroll
    for (int i = 0; i < 8; ++i) {
        const int lin = i * 256 + tid;
        const int r = lin >> 4, u = lin & 15;
        Bl[r * 16 + (u ^ (r & 7))] =
            *(const bf16x8*)(Wd + 65536 + (size_t)r * E_ + u * 8);
    }
    __syncthreads();
    #pragma unroll
    for (int nf = 0; nf < 8; ++nf) acc[nf] = f32x4{0.f, 0.f, 0.f, 0.f};
    #pragma unroll
    for (int s = 0; s < 4; ++s) {
        const int ua = s * 4 + g;
        const bf16x8 a = Al[mr * 16 + (ua ^ (mr & 7))];
        #pragma unroll
        for (int nf = 0; nf < 8; ++nf) {
            const int nr = nf * 16 + l15;
            acc[nf] = __builtin_amdgcn_mfma_f32_16x16x32_bf16(
                a, Bl[nr * 16 + (ua ^ (nr & 7))], acc[nf], 0, 0, 0);
        }
    }
    #pragma unroll
    for (int fr = 0; fr < 4; ++fr) {
        const int rloc = w * 16 + g * 4 + fr;
        #pragma unroll
        for (int nf = 0; nf < 8; ++nf) {
            const int col = nf * 16 + l15;
            const float f = fmaxf(acc[nf][fr] + b1[col], 0.f);
            const int u = col >> 3;
            Alb[(rloc * 16 + (u ^ (rloc & 7))) * 8 + (col & 7)] = __float2bfloat16(f);
        }
    }

    // ---- step 3: LN2(x1 + f1@W2 + b2) -> X ; pool partials in registers ----
    __syncthreads();
    #pragma unroll
    for (int i = 0; i < 8; ++i) {
        const int lin = i * 256 + tid;
        const int r = lin >> 4, u = lin & 15;
        Bl[r * 16 + (u ^ (r & 7))] =
            *(const bf16x8*)(Wd + 81920 + (size_t)r * E_ + u * 8);
    }
    __syncthreads();
    #pragma unroll
    for (int nf = 0; nf < 8; ++nf) acc[nf] = f32x4{0.f, 0.f, 0.f, 0.f};
    #pragma unroll
    for (int s = 0; s < 4; ++s) {
        const int ua = s * 4 + g;
        const bf16x8 a = Al[mr * 16 + (ua ^ (mr & 7))];
        #pragma unroll
        for (int nf = 0; nf < 8; ++nf) {
            const int nr = nf * 16 + l15;
            acc[nf] = __builtin_amdgcn_mfma_f32_16x16x32_bf16(
                a, Bl[nr * 16 + (ua ^ (nr & 7))], acc[nf], 0, 0, 0);
        }
    }
    float pp0[8] = {0.f, 0.f, 0.f, 0.f, 0.f, 0.f, 0.f, 0.f};
    float pp1[8] = {0.f, 0.f, 0.f, 0.f, 0.f, 0.f, 0.f, 0.f};
    #pragma unroll
    for (int fr = 0; fr < 4; ++fr) {
        const int grow = m0 + w * 16 + g * 4 + fr;
        const int bb = grow / S_, ss = grow - bb * S_;
        const int bl = bb - b0;
        float s1 = 0.f, s2 = 0.f;
        float v[8];
        #pragma unroll
        for (int nf = 0; nf < 8; ++nf) {
            const int col = nf * 16 + l15;
            const float xv = acc[nf][fr] + b2[col] + x1[nf][fr];
            v[nf] = xv; s1 += xv; s2 += xv * xv;
        }
        #pragma unroll
        for (int off = 1; off < 16; off <<= 1) {
            s1 += __shfl_xor(s1, off);
            s2 += __shfl_xor(s2, off);
        }
        const float mu = s1 * (1.f / 128.f);
        const float rstd = rsqrtf(s2 * (1.f / 128.f) - mu * mu + LN_EPS);
        #pragma unroll
        for (int nf = 0; nf < 8; ++nf) {
            const int col = nf * 16 + l15;
            const float xo = (v[nf] - mu) * rstd * ln2g[col] + ln2b[col];
            X[(size_t)grow * E_ + col] = xo;
            if (ss > 0) {                       // static-indexed partials (rule #20)
                if (bl == 0) pp0[nf] += xo;
                else         pp1[nf] += xo;
            }
        }
    }
    // reduce across g-groups (lanes ^16, ^32 share l15 and wave)
    #pragma unroll
    for (int nf = 0; nf < 8; ++nf) {
        pp0[nf] += __shfl_xor(pp0[nf], 16); pp0[nf] += __shfl_xor(pp0[nf], 32);
        pp1[nf] += __shfl_xor(pp1[nf], 16); pp1[nf] += __shfl_xor(pp1[nf], 32);
    }
    if (l < 16) {
        #pragma unroll
        for (int nf = 0; nf < 8; ++nf) {
            hbw[w][0][nf * 16 + l15] = pp0[nf];
            hbw[w][1][nf * 16 + l15] = pp1[nf];
        }
    }
    __syncthreads();
    {
        const int bl = tid >> 7, col = tid & 127;
        const int bb = b0 + bl;
        const float v = hbw[0][bl][col] + hbw[1][bl][col] +
                        hbw[2][bl][col] + hbw[3][bl][col];
        if (bb < B_) atomicAdd(&hb[bb * 128 + col], v * (1.f / 128.f));
    }
}

// ---------------------------------------------------------------------------
// MFMA attention v2 (round-9 proven version, unchanged)
// ---------------------------------------------------------------------------
__global__ __launch_bounds__(256)
void attn_mfma(bf16* __restrict__ qb, const bf16* __restrict__ kb,
               const bf16* __restrict__ vb) {
    __shared__ __align__(16) bf16x8 Ks[144 * 8];      // 18 KiB, swizzled
    __shared__ __align__(16) bf16  Vt[64 * 168];      // 21 KiB, V^T
    __shared__ __align__(16) bf16  Pb[4][16 * 168];   // 21 KiB, per-wave P
    const int tid = threadIdx.x;
    const int w = tid >> 6, l = tid & 63;
    const int l15 = l & 15, g = l >> 4;
    const int blk = blockIdx.x;
    const int half = blk & 1;
    const int h = (blk >> 1) & (H_ - 1);
    const int b = blk >> 2;
    const size_t base = ((size_t)b * S_) * E_ + h * HD;

    for (int idx = tid; idx < 144 * 8; idx += 256) {
        const int r = idx >> 3, u = idx & 7;
        bf16x8 kv = {0, 0, 0, 0, 0, 0, 0, 0};
        if (r < S_) kv = *(const bf16x8*)(kb + base + (size_t)r * E_ + u * 8);
        Ks[r * 8 + (u ^ (r & 7))] = kv;
    }
    for (int idx = tid; idx < 168 * 64; idx += 256) {
        const int t = idx >> 6, d = idx & 63;
        Vt[d * 168 + t] = (t < S_) ? vb[base + (size_t)t * E_ + d]
                                   : __float2bfloat16(0.f);
    }
    __syncthreads();

    bf16* P = Pb[w];
    for (int rt = (half ? 5 : 0) + w; rt < (half ? 9 : 5); rt += 4) {
        const int qr0 = rt * 16 + l15;
        const int qrow = (qr0 < S_) ? qr0 : (S_ - 1);
        const bf16x8 aq0 = *(const bf16x8*)(qb + base + (size_t)qrow * E_ + g * 8);
        const bf16x8 aq1 = *(const bf16x8*)(qb + base + (size_t)qrow * E_ + 32 + g * 8);

        f32x4 acc[9];
        #pragma unroll
        for (int ct = 0; ct < 9; ++ct) {
            const int kr = ct * 16 + l15;
            f32x4 a = {0.f, 0.f, 0.f, 0.f};
            a = __builtin_amdgcn_mfma_f32_16x16x32_bf16(
                    aq0, Ks[kr * 8 + (g ^ (kr & 7))], a, 0, 0, 0);
            a = __builtin_amdgcn_mfma_f32_16x16x32_bf16(
                    aq1, Ks[kr * 8 + ((4 + g) ^ (kr & 7))], a, 0, 0, 0);
            acc[ct] = a;
        }

        const bool tail = (l15 != 0);
        float mx[4] = {-1e30f, -1e30f, -1e30f, -1e30f};
        #pragma unroll
        for (int ct = 0; ct < 9; ++ct)
            #pragma unroll
            for (int r = 0; r < 4; ++r) {
                const float v = acc[ct][r] * 0.125f;
                acc[ct][r] = v;
                if (ct < 8 || !tail) mx[r] = fmaxf(mx[r], v);
            }
        #pragma unroll
        for (int r = 0; r < 4; ++r)
            #pragma unroll
            for (int off = 1; off < 16; off <<= 1)
                mx[r] = fmaxf(mx[r], __shfl_xor(mx[r], off));
        float sm[4] = {0.f, 0.f, 0.f, 0.f};
        #pragma unroll
        for (int ct = 0; ct < 9; ++ct)
            #pragma unroll
            for (int r = 0; r < 4; ++r) {
                const float p = (ct < 8 || !tail) ? __expf(acc[ct][r] - mx[r]) : 0.f;
                acc[ct][r] = p;
                sm[r] += p;
            }
        #pragma unroll
        for (int r = 0; r < 4; ++r) {
            #pragma unroll
            for (int off = 1; off < 16; off <<= 1)
                sm[r] += __shfl_xor(sm[r], off);
            sm[r] = 1.f / sm[r];
        }

        #pragma unroll
        for (int ct = 0; ct < 9; ++ct)
            #pragma unroll
            for (int r = 0; r < 4; ++r)
                P[(g * 4 + r) * 168 + ct * 16 + l15] =
                    __float2bfloat16(acc[ct][r] * sm[r]);
        #pragma unroll
        for (int r = 0; r < 4; ++r)
            P[(g * 4 + r) * 168 + 144 + l15] = __float2bfloat16(0.f);

        #pragma unroll
        for (int co = 0; co < 4; ++co) {
            f32x4 o = {0.f, 0.f, 0.f, 0.f};
            #pragma unroll
            for (int kc = 0; kc < 5; ++kc) {
                const bf16x8 pa = *(const bf16x8*)(P + l15 * 168 + kc * 32 + g * 8);
                const bf16x8 vv = *(const bf16x8*)(Vt + (co * 16 + l15) * 168 + kc * 32 + g * 8);
                o = __builtin_amdgcn_mfma_f32_16x16x32_bf16(pa, vv, o, 0, 0, 0);
            }
            #pragma unroll
            for (int r = 0; r < 4; ++r) {
                const int orow = rt * 16 + g * 4 + r;
                if (orow < S_)
                    qb[base + (size_t)orow * E_ + co * 16 + l15] =
                        __float2bfloat16(o[r]);
            }
        }
    }
}

// ---------------------------------------------------------------------------
extern "C" void kernel_launch(void* const* d_in, const int* in_sizes, int n_in,
                              void* d_out, int out_size, void* d_ws, size_t ws_size,
                              hipStream_t stream) {
    const int* cat_arr      = (const int*)d_in[0];
    const int* dt_arr       = (const int*)d_in[1];
    const int* amount_arr   = (const int*)d_in[2];
    const int* id_arr       = (const int*)d_in[3];
    const float* id_table   = (const float*)d_in[4];
    const float* cat_table  = (const float*)d_in[5];
    const float* amount_tab = (const float*)d_in[6];
    const float* dt_table   = (const float*)d_in[7];
    const float* Wq = (const float*)d_in[8];  const float* bq = (const float*)d_in[9];
    const float* Wk = (const float*)d_in[10]; const float* bk = (const float*)d_in[11];
    const float* Wv = (const float*)d_in[12]; const float* bv = (const float*)d_in[13];
    const float* Wo = (const float*)d_in[14]; const float* bo = (const float*)d_in[15];
    const float* ln1_g = (const float*)d_in[16]; const float* ln1_b = (const float*)d_in[17];
    const float* W1 = (const float*)d_in[18]; const float* b1 = (const float*)d_in[19];
    const float* W2 = (const float*)d_in[20]; const float* b2 = (const float*)d_in[21];
    const float* ln2_g = (const float*)d_in[22]; const float* ln2_b = (const float*)d_in[23];
    const float* lin1_W = (const float*)d_in[24]; const float* lin1_b = (const float*)d_in[25];
    const float* lin2_W = (const float*)d_in[26]; const float* lin2_b = (const float*)d_in[27];
    float* out = (float*)d_out;
    float* ws = (float*)d_ws;

    // Workspace (floats), total ~22.9 MiB:
    //   X[ME] | C0 bf16[ME] | D0 bf16[ME] | E0 bf16[ME] | Wd | bias1024 | catb | amtb | hb
    const size_t ME = (size_t)M_ * E_;           // 2,113,536
    float* X  = ws;                               // f32 x -> x2 (in-place)
    bf16* C0  = (bf16*)(ws + ME);                 // Kb
    bf16* D0  = (bf16*)(ws + ME + ME / 2);        // Qb -> Ob -> a1b
    bf16* E0  = (bf16*)(ws + 2 * ME);             // Vb
    bf16* Wd  = (bf16*)(ws + 2 * ME + ME / 2);    // 1,277,952 bf16
    float* bias1024 = ws + 2 * ME + ME / 2 + 638976;
    bf16* catb = (bf16*)(bias1024 + 1024);        // [1000][128] bf16
    bf16* amtb = catb + 128000;                   // [100][128] bf16
    float* hb  = (float*)(amtb + 12800);          // [128][128] f32
    bf16* a1b = D0 + 16384;                       // [128][1024]

    prep_kernel<<<dim3(16, 16, 12), 256, 0, stream>>>(
        Wq, Wk, Wv, Wo, W1, W2, lin1_W, lin2_W, lin1_b, lin2_b,
        cat_table, amount_tab, Wd, bias1024, catb, amtb, hb, out);

    embed_kernel<<<M_ / 2, 256, 0, stream>>>(cat_arr, dt_arr, amount_arr, id_arr,
                                             id_table, catb, amtb, dt_table, X);

    // Fused QKV from f32 X: sel 0->Q(D0), 1->K(C0), 2->V(E0)
    gemm_mfma<false,false,false,false,true,false,true,true,false>
        <<<dim3(M_ / 64, 3), 256, 0, stream>>>(
        X, Wd, bq, bk, bv, nullptr, nullptr, D0, C0, E0, nullptr, nullptr,
        128, 128, 128);

    attn_mfma<<<B_ * H_ * 2, 256, 0, stream>>>(D0, C0, E0);   // Ob -> D0

    // Fused tail + pool: X = LN2(...), hb += pooled means (hb zeroed by prep)
    encoder_tail<<<M_ / 64, 256, 0, stream>>>(
        D0, Wd, bo, b1, b2, ln1_g, ln1_b, ln2_g, ln2_b, X, hb);

    // a1b = relu(hb@lin1 + b) [128][1024] (A is f32 via AF32 staging)
    gemm_mfma<true,false,false,false,true,false,true,false,false>
        <<<dim3(2, 8), 256, 0, stream>>>(
        hb, Wd + 98304, bias1024, nullptr, nullptr, nullptr, nullptr, a1b,
        nullptr, nullptr, nullptr, nullptr, 128, 1024, 1024);
    // out += a1b@lin2 partials (K=1024 split 8 ways, atomic; out pre-set to bias)
    gemm_mfma<false,false,false,true,false,true,false,false,true>
        <<<dim3(2, 8, 8), 256, 0, stream>>>(
        a1b, Wd + 229376, nullptr, nullptr, nullptr, nullptr, out, nullptr,
        nullptr, nullptr, nullptr, nullptr, 1024, 1000, 1000);
}